// Round 10
// baseline (551.479 us; speedup 1.0000x reference)
//
#include <hip/hip_runtime.h>
#include <hip/hip_bf16.h>

#define B_ 32
#define S_ 256
#define E_ 768
#define H_ 32
#define D_ 24
#define NTOT 1664   // 768 (q) + 768 (k) + 96 (vw) + 32 pad

typedef __hip_bfloat16 bf16;
typedef __attribute__((ext_vector_type(8))) short short8;
typedef __attribute__((ext_vector_type(4))) float floatx4;
typedef __attribute__((ext_vector_type(2))) float f32x2;

// global_load_lds width=16: wave-uniform LDS base + lane*16B linear dest.
#define GLOAD_LDS16(g, l)                                          \
  __builtin_amdgcn_global_load_lds(                                \
      (const __attribute__((address_space(1))) void*)(g),          \
      (__attribute__((address_space(3))) void*)(l), 16, 0, 0)

// ---------------------------------------------------------------------------
// feats fp32 -> bf16, 4 elems/thread
// ---------------------------------------------------------------------------
__global__ __launch_bounds__(256) void cast_feats(
    const float* __restrict__ in, bf16* __restrict__ outp, int n4)
{
  int i = blockIdx.x * 256 + threadIdx.x;
  if (i < n4) {
    float4 v = reinterpret_cast<const float4*>(in)[i];
    union { ushort4 u; bf16 b[4]; } pk;
    pk.b[0] = (bf16)v.x; pk.b[1] = (bf16)v.y;
    pk.b[2] = (bf16)v.z; pk.b[3] = (bf16)v.w;
    reinterpret_cast<ushort4*>(outp)[i] = pk.u;
  }
}

// ---------------------------------------------------------------------------
// prep_qk: LDS-tiled 64x64 transpose of Wq/Wk -> Wt[n][k] bf16 (q rows
// pre-scaled by 24^-0.5). Coalesced read/write, 65-pad conflict-free.
// ---------------------------------------------------------------------------
__global__ __launch_bounds__(256) void prep_qk(
    const float* __restrict__ Wq, const float* __restrict__ Wk,
    bf16* __restrict__ Wt)
{
  __shared__ float tile[64][65];
  int n0 = blockIdx.x * 64;          // 0..1535 (q: <768, k: >=768)
  int k0 = blockIdx.y * 64;          // 0..767
  int j = threadIdx.x & 63, i4 = threadIdx.x >> 6;
  const float qscale = 0.20412414523193154f;  // 24^-0.5
  bool isq = (n0 < 768);             // uniform: tiles never straddle 768
  const float* W = isq ? Wq : Wk;
  int nc = isq ? n0 : n0 - 768;
  float sc = isq ? qscale : 1.0f;
  #pragma unroll
  for (int r = 0; r < 16; r++) {
    int i = r * 4 + i4;
    tile[i][j] = W[(size_t)(k0 + i) * E_ + nc + j] * sc;
  }
  __syncthreads();
  #pragma unroll
  for (int r = 0; r < 16; r++) {
    int jj = r * 4 + i4;
    Wt[(size_t)(n0 + jj) * E_ + k0 + j] = (bf16)tile[j][jj];
  }
}

// ---------------------------------------------------------------------------
// prep_vw_bias: fused Wv*Wf rows (n in [1536,1632)), zero pad rows, and the
// fused bias vector biasf[NTOT].
// ---------------------------------------------------------------------------
__global__ __launch_bounds__(256) void prep_vw_bias(
    const float* __restrict__ Wv,
    const float* __restrict__ bq, const float* __restrict__ bk,
    const float* __restrict__ bv,
    const float* __restrict__ Wfx, const float* __restrict__ Wfy,
    const float* __restrict__ Wfz,
    bf16* __restrict__ Wt, float* __restrict__ biasf)
{
  const float qscale = 0.20412414523193154f;
  int gid = blockIdx.x * 256 + threadIdx.x;
  if (gid < 128 * E_) {
    int n = 1536 + gid / E_, k = gid % E_;
    float val = 0.f;
    if (n < 1632) {
      int nn = n - 1536, x = nn >> 5, h = nn & 31;
      const float* Wf = (x == 0) ? Wfx : (x == 1 ? Wfy : Wfz);
      #pragma unroll
      for (int c = 0; c < D_; c++)
        val += Wv[(size_t)k * E_ + h * D_ + c] * Wf[h * D_ + c];
    }
    Wt[(size_t)n * E_ + k] = (bf16)val;
  } else {
    int n = gid - 128 * E_;
    if (n < NTOT) {
      float val;
      if (n < 768) {
        val = bq[n] * qscale;
      } else if (n < 1536) {
        val = bk[n - 768];
      } else if (n < 1632) {
        int nn = n - 1536, x = nn >> 5, h = nn & 31;
        const float* Wf = (x == 0) ? Wfx : (x == 1 ? Wfy : Wfz);
        float s = 0.f;
        #pragma unroll
        for (int c = 0; c < D_; c++)
          s += bv[h * D_ + c] * Wf[h * D_ + c];
        val = s;
      } else {
        val = 0.f;
      }
      biasf[n] = val;
    }
  }
}

// ---------------------------------------------------------------------------
// gemm_qkv v9: m97-recipe staging. Per K-step each thread issues 4x
// global_load_lds width=16 (no VGPR round-trip, no ds_write). LDS rows are
// LK=32 (64B, un-padded) for the linear DMA destination; bank conflicts
// fixed the both-sides-or-neither way: source chunk XOR (lane&3)^(row&3)
// pre-swizzles the GLOBAL address, fragment reads apply the same involution
// -> 8-way conflict becomes 2-way (free). LDS 16KB/block.
// Epilogue writes q/k in [b][s][E] (coalesced 32B runs).
// ---------------------------------------------------------------------------
__global__ __launch_bounds__(256) void gemm_qkv(
    const bf16* __restrict__ A, const bf16* __restrict__ Wt,
    const float* __restrict__ biasf,
    bf16* __restrict__ qout, bf16* __restrict__ kout,
    float* __restrict__ vwout)
{
  __shared__ __align__(16) short As[128 * 32];
  __shared__ __align__(16) short Bs[128 * 32];
  int tid = threadIdx.x;
  int m0 = blockIdx.y * 128, n0 = blockIdx.x * 128;
  int wave = tid >> 6, lane = tid & 63;
  int wm = (wave >> 1) * 64, wn = (wave & 1) * 64;
  int fr = lane & 15, quad = lane >> 4;

  // staging geometry: wave w stages rows w*32..w*32+31 (2 calls x 16 rows).
  // row&3 is invariant under +16, so the source-XOR chunk is call-invariant.
  int srow = wave * 32 + (lane >> 2);
  int schunk = (lane & 3) ^ (srow & 3);          // XOR-swizzled source chunk
  const bf16* Asrc = A + (size_t)(m0 + srow) * E_ + schunk * 8;
  const bf16* Bsrc = Wt + (size_t)(n0 + srow) * E_ + schunk * 8;
  short* AsW = As + wave * 1024;                 // 2KB per wave
  short* BsW = Bs + wave * 1024;

  floatx4 acc[4][4];
  const floatx4 zero = {0.f, 0.f, 0.f, 0.f};
  #pragma unroll
  for (int i = 0; i < 4; i++)
    #pragma unroll
    for (int j = 0; j < 4; j++) acc[i][j] = zero;

  // fragment read offsets with the same involution on the read side
  int ra[4], rb[4];
  #pragma unroll
  for (int t = 0; t < 4; t++) {
    int rowa = wm + t * 16 + fr;
    int rowb = wn + t * 16 + fr;
    ra[t] = rowa * 32 + (quad ^ (rowa & 3)) * 8;
    rb[t] = rowb * 32 + (quad ^ (rowb & 3)) * 8;
  }

  for (int k0 = 0; k0 < E_; k0 += 32) {
    if (k0) __syncthreads();        // previous iter's frag reads complete
    GLOAD_LDS16(Asrc + k0, AsW);
    GLOAD_LDS16(Asrc + (size_t)16 * E_ + k0, AsW + 512);
    GLOAD_LDS16(Bsrc + k0, BsW);
    GLOAD_LDS16(Bsrc + (size_t)16 * E_ + k0, BsW + 512);
    __syncthreads();                // vmcnt(0) drained before barrier
    short8 af[4], bfr[4];
    #pragma unroll
    for (int t = 0; t < 4; t++)
      af[t] = *reinterpret_cast<const short8*>(&As[ra[t]]);
    #pragma unroll
    for (int t = 0; t < 4; t++)
      bfr[t] = *reinterpret_cast<const short8*>(&Bs[rb[t]]);
    #pragma unroll
    for (int ti = 0; ti < 4; ti++)
      #pragma unroll
      for (int tj = 0; tj < 4; tj++)
        acc[ti][tj] = __builtin_amdgcn_mfma_f32_16x16x32_bf16(
            af[ti], bfr[tj], acc[ti][tj], 0, 0, 0);
  }

  // epilogue: C/D layout col = lane&15, row = quad*4 + r
  #pragma unroll
  for (int ti = 0; ti < 4; ti++) {
    #pragma unroll
    for (int tj = 0; tj < 4; tj++) {
      int n = n0 + wn + tj * 16 + fr;
      float bias = biasf[n];
      #pragma unroll
      for (int r = 0; r < 4; r++) {
        int m = m0 + wm + ti * 16 + quad * 4 + r;
        int b = m >> 8, s = m & 255;
        float val = acc[ti][tj][r] + bias;
        if (n < 768) {
          qout[(size_t)(b * S_ + s) * E_ + n] = (bf16)val;
        } else if (n < 1536) {
          kout[(size_t)(b * S_ + s) * E_ + (n - 768)] = (bf16)val;
        } else if (n < 1632) {
          int nn = n - 1536, x = nn >> 5, hh = nn & 31;
          vwout[(((size_t)x * B_ + b) * H_ + hh) * S_ + s] = val;
        }
      }
    }
  }
}

// ---------------------------------------------------------------------------
// Attention v9 = v6 structure (wave-owns-s, lanes-own-t, coalesced streams,
// shifted softmax, 4 parallel butterflies, 1-DEEP rolled prefetch — measured
// 175us @ 84 VGPR / 31% occ; the 2-deep variant cost occupancy 31->21% and
// was net-negative) with v7's [b][s][E] q/k addressing.
// ---------------------------------------------------------------------------
__global__ __launch_bounds__(256) void attn_kernel(
    const bf16* __restrict__ qg, const bf16* __restrict__ kg,
    const float* __restrict__ vwg, const float* __restrict__ biasg,
    const float* __restrict__ dpg, float* __restrict__ part)
{
  __shared__ __align__(16) float ql[64 * 26];
  int blk = blockIdx.x;             // 0..4095
  int b = blk & 31;                 // same-b -> same XCD (blk%8 == b%8)
  int u = blk >> 5;
  int h = u & 31;
  int st = (u >> 5) * 64;           // s-tile: 0,64,128,192
  int bh = b * H_ + h;
  int tid = threadIdx.x, wave = tid >> 6, lane = tid & 63;
  int t0 = lane * 4;

  // ---- K rows t0..t0+3 -> f32x2 regs ([b][t][E], 48B runs) ----
  f32x2 kr[4][12];
  #pragma unroll
  for (int j = 0; j < 4; j++) {
    const short8* kp = reinterpret_cast<const short8*>(
        kg + (size_t)(b * S_ + t0 + j) * E_ + h * D_);
    #pragma unroll
    for (int seg = 0; seg < 3; seg++) {
      short8 kk = kp[seg];
      #pragma unroll
      for (int p2 = 0; p2 < 4; p2++) {
        union { short u; bf16 bb; } a, c;
        a.u = kk[2 * p2]; c.u = kk[2 * p2 + 1];
        f32x2 t2; t2.x = (float)a.bb; t2.y = (float)c.bb;
        kr[j][seg * 4 + p2] = t2;
      }
    }
  }
  // ---- vw for this lane's 4 t's, 3 dims ----
  float vwr[3][4];
  #pragma unroll
  for (int x = 0; x < 3; x++) {
    float4 v4 = *reinterpret_cast<const float4*>(
        vwg + (((size_t)x * B_ + b) * H_ + h) * S_ + t0);
    vwr[x][0] = v4.x; vwr[x][1] = v4.y; vwr[x][2] = v4.z; vwr[x][3] = v4.w;
  }
  // ---- stage q tile (64 rows x 24) as f32 in LDS ----
  {
    int r = tid >> 2, c0 = (tid & 3) * 6;
    const bf16* qrow = qg + (size_t)(b * S_ + st + r) * E_ + h * D_ + c0;
    #pragma unroll
    for (int i = 0; i < 6; i++) ql[r * 26 + c0 + i] = (float)qrow[i];
  }
  __syncthreads();

  const float* biasbh = biasg + (size_t)bh * S_ * S_;
  const float* dpb    = dpg + (size_t)b * S_ * S_ * 3;

  // 1-deep prefetch (iteration 0, row = wave)
  float4 nb, nd0, nd1, nd2;
  {
    int s0 = st + wave;
    nb = *reinterpret_cast<const float4*>(biasbh + (size_t)s0 * S_ + t0);
    const float* dpr = dpb + (size_t)s0 * S_ * 3 + (size_t)t0 * 3;
    nd0 = *reinterpret_cast<const float4*>(dpr);
    nd1 = *reinterpret_cast<const float4*>(dpr + 4);
    nd2 = *reinterpret_cast<const float4*>(dpr + 8);
  }

  for (int si = 0; si < 16; si++) {
    float4 bias4 = nb, e0 = nd0, e1 = nd1, e2 = nd2;
    // issue next row's loads before compute
    int nsi = (si + 1 < 16) ? si + 1 : 0;    // last iter: dummy (L2-hot)
    int ns = st + nsi * 4 + wave;
    nb = *reinterpret_cast<const float4*>(biasbh + (size_t)ns * S_ + t0);
    const float* dpn = dpb + (size_t)ns * S_ * 3 + (size_t)t0 * 3;
    nd0 = *reinterpret_cast<const float4*>(dpn);
    nd1 = *reinterpret_cast<const float4*>(dpn + 4);
    nd2 = *reinterpret_cast<const float4*>(dpn + 8);

    int sr = si * 4 + wave;                  // row within tile
    int s  = st + sr;

    // scores for this lane's 4 t's (q broadcast from LDS, K in regs)
    f32x2 sc2[4];
    #pragma unroll
    for (int j = 0; j < 4; j++) { sc2[j].x = 0.f; sc2[j].y = 0.f; }
    #pragma unroll
    for (int i = 0; i < 12; i++) {
      f32x2 qd = *reinterpret_cast<const f32x2*>(&ql[sr * 26 + 2 * i]);
      #pragma unroll
      for (int j = 0; j < 4; j++) sc2[j] += qd * kr[j][i];
    }
    // constant shift -4 == exact softmax (scores O(10), fp32 range safe)
    float p[4];
    p[0] = __expf(sc2[0].x + sc2[0].y + bias4.x - 4.0f);
    p[1] = __expf(sc2[1].x + sc2[1].y + bias4.y - 4.0f);
    p[2] = __expf(sc2[2].x + sc2[2].y + bias4.z - 4.0f);
    p[3] = __expf(sc2[3].x + sc2[3].y + bias4.w - 4.0f);
    float l = (p[0] + p[1]) + (p[2] + p[3]);

    // dp unpack (t-major xyz) from the 3 float4s
    float dx[4] = {e0.x, e0.w, e1.z, e2.y};
    float dy[4] = {e0.y, e1.x, e1.w, e2.z};
    float dz[4] = {e0.z, e1.y, e2.x, e2.w};

    float ax = 0.f, ay = 0.f, az = 0.f;
    #pragma unroll
    for (int j = 0; j < 4; j++) {
      ax = fmaf(p[j] * dx[j], vwr[0][j], ax);
      ay = fmaf(p[j] * dy[j], vwr[1][j], ay);
      az = fmaf(p[j] * dz[j], vwr[2][j], az);
    }
    // 4 parallel butterflies
    #pragma unroll
    for (int o = 32; o; o >>= 1) {
      ax += __shfl_xor(ax, o);
      ay += __shfl_xor(ay, o);
      az += __shfl_xor(az, o);
      l  += __shfl_xor(l, o);
    }
    if (lane == 0) {
      float inv = 1.0f / l;
      float* op = part + ((size_t)bh * S_ + s) * 3;
      op[0] = ax * inv; op[1] = ay * inv; op[2] = az * inv;
    }
  }
}

// ---------------------------------------------------------------------------
// Sum partials over h: out[b][s][x] = sum_h part[(b*H+h)][s][x].
// Every d_out element written exactly once (tripwire-safe, no atomics).
// ---------------------------------------------------------------------------
__global__ __launch_bounds__(256) void reduce_h(
    const float* __restrict__ part, float* __restrict__ out)
{
  int k = blockIdx.x * 256 + threadIdx.x;   // 0 .. B_*S_*3-1 (grid exact)
  int b = k / (S_ * 3);
  int r = k - b * (S_ * 3);                 // s*3 + x
  const float* p = part + (size_t)b * H_ * S_ * 3 + r;
  float acc = 0.f;
  #pragma unroll
  for (int h = 0; h < H_; h++) acc += p[(size_t)h * S_ * 3];
  out[k] = acc;
}

// ---------------------------------------------------------------------------
extern "C" void kernel_launch(void* const* d_in, const int* in_sizes, int n_in,
                              void* d_out, int out_size, void* d_ws, size_t ws_size,
                              hipStream_t stream)
{
  const float* feats     = (const float*)d_in[0];
  const float* attn_bias = (const float*)d_in[1];
  const float* delta_pos = (const float*)d_in[2];
  const float* Wq        = (const float*)d_in[3];
  const float* bq        = (const float*)d_in[4];
  const float* Wk        = (const float*)d_in[5];
  const float* bk        = (const float*)d_in[6];
  const float* Wv        = (const float*)d_in[7];
  const float* bv        = (const float*)d_in[8];
  const float* Wfx       = (const float*)d_in[9];
  const float* Wfy       = (const float*)d_in[10];
  const float* Wfz       = (const float*)d_in[11];

  char* ws = (char*)d_ws;
  size_t off = 0;
  auto alloc = [&](size_t bytes) -> void* {
    void* p = ws + off;
    off = (off + bytes + 255) & ~(size_t)255;
    return p;
  };
  bf16*  ws_fb   = (bf16*) alloc((size_t)B_ * S_ * E_ * 2);        // feats bf16
  bf16*  ws_q    = (bf16*) alloc((size_t)B_ * S_ * E_ * 2);        // q [b][s][E]
  bf16*  ws_k    = (bf16*) alloc((size_t)B_ * S_ * E_ * 2);        // k [b][s][E]
  float* ws_vw   = (float*)alloc((size_t)3 * B_ * H_ * S_ * 4);
  bf16*  ws_Wt   = (bf16*) alloc((size_t)NTOT * E_ * 2);
  float* ws_bias = (float*)alloc((size_t)NTOT * 4);
  float* ws_part = (float*)alloc((size_t)B_ * H_ * S_ * 3 * 4);    // h-partials

  int n4 = B_ * S_ * E_ / 4;
  cast_feats<<<(n4 + 255) / 256, 256, 0, stream>>>(feats, ws_fb, n4);

  prep_qk<<<dim3(24, 12), 256, 0, stream>>>(Wq, Wk, ws_Wt);

  int prep_n = 128 * E_ + NTOT;
  prep_vw_bias<<<(prep_n + 255) / 256, 256, 0, stream>>>(
      Wv, bq, bk, bv, Wfx, Wfy, Wfz, ws_Wt, ws_bias);

  gemm_qkv<<<dim3(NTOT / 128, B_ * S_ / 128), 256, 0, stream>>>(
      ws_fb, ws_Wt, ws_bias, ws_q, ws_k, ws_vw);

  attn_kernel<<<B_ * H_ * 4, 256, 0, stream>>>(ws_q, ws_k, ws_vw, attn_bias,
                                               delta_pos, ws_part);

  reduce_h<<<(B_ * S_ * 3) / 256, 256, 0, stream>>>(ws_part, (float*)d_out);
}

// Round 11
// 539.250 us; speedup vs baseline: 1.0227x; 1.0227x over previous
//
#include <hip/hip_runtime.h>
#include <hip/hip_bf16.h>

#define B_ 32
#define S_ 256
#define E_ 768
#define H_ 32
#define D_ 24
#define NTOT 1664   // 768 (q) + 768 (k) + 96 (vw) + 32 pad

typedef __hip_bfloat16 bf16;
typedef __attribute__((ext_vector_type(8))) short short8;
typedef __attribute__((ext_vector_type(4))) float floatx4;
typedef __attribute__((ext_vector_type(2))) float f32x2;

// global_load_lds width=16: wave-uniform LDS base + lane*16B linear dest.
#define GLOAD_LDS16(g, l)                                          \
  __builtin_amdgcn_global_load_lds(                                \
      (const __attribute__((address_space(1))) void*)(g),          \
      (__attribute__((address_space(3))) void*)(l), 16, 0, 0)

// grid partition of the fused prep kernel
#define CAST_BLKS 6144   // B*S*E/4/256
#define QK_BLKS   288    // 24 x 12 tiles of 64x64
#define VW_BLKS   391    // (128*E + NTOT + 255)/256

// ---------------------------------------------------------------------------
// prep_fused: three independent upstream kernels merged into one dispatch
// (node-count test: 6 graph nodes -> 4). Sections are verbatim copies:
//   [0, CAST)          feats fp32 -> bf16, 4 elems/thread
//   [CAST, CAST+QK)    LDS-tiled 64x64 transpose Wq/Wk -> Wt (q pre-scaled)
//   [CAST+QK, ...)     fused Wv*Wf rows + pad + bias vector
// ---------------------------------------------------------------------------
__global__ __launch_bounds__(256) void prep_fused(
    const float* __restrict__ feats, bf16* __restrict__ fb,
    const float* __restrict__ Wq, const float* __restrict__ Wk,
    const float* __restrict__ Wv,
    const float* __restrict__ bq, const float* __restrict__ bk,
    const float* __restrict__ bv,
    const float* __restrict__ Wfx, const float* __restrict__ Wfy,
    const float* __restrict__ Wfz,
    bf16* __restrict__ Wt, float* __restrict__ biasf)
{
  __shared__ float tile[64][65];
  const float qscale = 0.20412414523193154f;  // 24^-0.5
  int bid = blockIdx.x;

  if (bid < CAST_BLKS) {
    // ---- cast_feats ----
    int i = bid * 256 + threadIdx.x;          // i < 1572864 always
    float4 v = reinterpret_cast<const float4*>(feats)[i];
    union { ushort4 u; bf16 b[4]; } pk;
    pk.b[0] = (bf16)v.x; pk.b[1] = (bf16)v.y;
    pk.b[2] = (bf16)v.z; pk.b[3] = (bf16)v.w;
    reinterpret_cast<ushort4*>(fb)[i] = pk.u;
    return;
  }
  if (bid < CAST_BLKS + QK_BLKS) {
    // ---- prep_qk (64x64 transpose tile) ----
    int id = bid - CAST_BLKS;
    int n0 = (id % 24) * 64;                  // 0..1535
    int k0 = (id / 24) * 64;                  // 0..767
    int j = threadIdx.x & 63, i4 = threadIdx.x >> 6;
    bool isq = (n0 < 768);                    // uniform per block
    const float* W = isq ? Wq : Wk;
    int nc = isq ? n0 : n0 - 768;
    float sc = isq ? qscale : 1.0f;
    #pragma unroll
    for (int r = 0; r < 16; r++) {
      int i = r * 4 + i4;
      tile[i][j] = W[(size_t)(k0 + i) * E_ + nc + j] * sc;
    }
    __syncthreads();
    #pragma unroll
    for (int r = 0; r < 16; r++) {
      int jj = r * 4 + i4;
      Wt[(size_t)(n0 + jj) * E_ + k0 + j] = (bf16)tile[j][jj];
    }
    return;
  }
  // ---- prep_vw_bias ----
  int gid = (bid - CAST_BLKS - QK_BLKS) * 256 + threadIdx.x;
  if (gid < 128 * E_) {
    int n = 1536 + gid / E_, k = gid % E_;
    float val = 0.f;
    if (n < 1632) {
      int nn = n - 1536, x = nn >> 5, h = nn & 31;
      const float* Wf = (x == 0) ? Wfx : (x == 1 ? Wfy : Wfz);
      #pragma unroll
      for (int c = 0; c < D_; c++)
        val += Wv[(size_t)k * E_ + h * D_ + c] * Wf[h * D_ + c];
    }
    Wt[(size_t)n * E_ + k] = (bf16)val;
  } else {
    int n = gid - 128 * E_;
    if (n < NTOT) {
      float val;
      if (n < 768) {
        val = bq[n] * qscale;
      } else if (n < 1536) {
        val = bk[n - 768];
      } else if (n < 1632) {
        int nn = n - 1536, x = nn >> 5, h = nn & 31;
        const float* Wf = (x == 0) ? Wfx : (x == 1 ? Wfy : Wfz);
        float s = 0.f;
        #pragma unroll
        for (int c = 0; c < D_; c++)
          s += bv[h * D_ + c] * Wf[h * D_ + c];
        val = s;
      } else {
        val = 0.f;
      }
      biasf[n] = val;
    }
  }
}

// ---------------------------------------------------------------------------
// gemm_qkv v10: v9 DMA staging (global_load_lds width=16, both-sides XOR
// swizzle, 16KB LDS) with the R5 epilogue restored: q/k written [bh][t][D]
// (the [b][s][E] layout cost attn 15us and bought gemm nothing — concluded).
// ---------------------------------------------------------------------------
__global__ __launch_bounds__(256) void gemm_qkv(
    const bf16* __restrict__ A, const bf16* __restrict__ Wt,
    const float* __restrict__ biasf,
    bf16* __restrict__ qout, bf16* __restrict__ kout,
    float* __restrict__ vwout)
{
  __shared__ __align__(16) short As[128 * 32];
  __shared__ __align__(16) short Bs[128 * 32];
  int tid = threadIdx.x;
  int m0 = blockIdx.y * 128, n0 = blockIdx.x * 128;
  int wave = tid >> 6, lane = tid & 63;
  int wm = (wave >> 1) * 64, wn = (wave & 1) * 64;
  int fr = lane & 15, quad = lane >> 4;

  // staging: wave w stages rows w*32..w*32+31 (2 calls x 16 rows).
  // row&3 invariant under +16 -> source-XOR chunk is call-invariant.
  int srow = wave * 32 + (lane >> 2);
  int schunk = (lane & 3) ^ (srow & 3);          // XOR-swizzled source chunk
  const bf16* Asrc = A + (size_t)(m0 + srow) * E_ + schunk * 8;
  const bf16* Bsrc = Wt + (size_t)(n0 + srow) * E_ + schunk * 8;
  short* AsW = As + wave * 1024;                 // 2KB per wave
  short* BsW = Bs + wave * 1024;

  floatx4 acc[4][4];
  const floatx4 zero = {0.f, 0.f, 0.f, 0.f};
  #pragma unroll
  for (int i = 0; i < 4; i++)
    #pragma unroll
    for (int j = 0; j < 4; j++) acc[i][j] = zero;

  // fragment read offsets with the same involution on the read side
  int ra[4], rb[4];
  #pragma unroll
  for (int t = 0; t < 4; t++) {
    int rowa = wm + t * 16 + fr;
    int rowb = wn + t * 16 + fr;
    ra[t] = rowa * 32 + (quad ^ (rowa & 3)) * 8;
    rb[t] = rowb * 32 + (quad ^ (rowb & 3)) * 8;
  }

  for (int k0 = 0; k0 < E_; k0 += 32) {
    if (k0) __syncthreads();        // previous iter's frag reads complete
    GLOAD_LDS16(Asrc + k0, AsW);
    GLOAD_LDS16(Asrc + (size_t)16 * E_ + k0, AsW + 512);
    GLOAD_LDS16(Bsrc + k0, BsW);
    GLOAD_LDS16(Bsrc + (size_t)16 * E_ + k0, BsW + 512);
    __syncthreads();                // vmcnt(0) drained before barrier
    short8 af[4], bfr[4];
    #pragma unroll
    for (int t = 0; t < 4; t++)
      af[t] = *reinterpret_cast<const short8*>(&As[ra[t]]);
    #pragma unroll
    for (int t = 0; t < 4; t++)
      bfr[t] = *reinterpret_cast<const short8*>(&Bs[rb[t]]);
    #pragma unroll
    for (int ti = 0; ti < 4; ti++)
      #pragma unroll
      for (int tj = 0; tj < 4; tj++)
        acc[ti][tj] = __builtin_amdgcn_mfma_f32_16x16x32_bf16(
            af[ti], bfr[tj], acc[ti][tj], 0, 0, 0);
  }

  // epilogue: C/D layout col = lane&15, row = quad*4 + r; [bh][t][D] writes
  #pragma unroll
  for (int ti = 0; ti < 4; ti++) {
    #pragma unroll
    for (int tj = 0; tj < 4; tj++) {
      int n = n0 + wn + tj * 16 + fr;
      float bias = biasf[n];
      #pragma unroll
      for (int r = 0; r < 4; r++) {
        int m = m0 + wm + ti * 16 + quad * 4 + r;
        int b = m >> 8, s = m & 255;
        float val = acc[ti][tj][r] + bias;
        if (n < 768) {
          int h = n / 24, d = n - h * 24;
          qout[(((size_t)b * H_ + h) * S_ + s) * D_ + d] = (bf16)val;
        } else if (n < 1536) {
          int n2 = n - 768;
          int h = n2 / 24, d = n2 - h * 24;
          kout[(((size_t)b * H_ + h) * S_ + s) * D_ + d] = (bf16)val;
        } else if (n < 1632) {
          int nn = n - 1536, x = nn >> 5, hh = nn & 31;
          vwout[(((size_t)x * B_ + b) * H_ + hh) * S_ + s] = val;
        }
      }
    }
  }
}

// ---------------------------------------------------------------------------
// Attention v11 = R5's measured-175us kernel verbatim: wave-owns-s,
// lanes-own-t, coalesced bias/dp streams, shifted softmax, 4 parallel
// butterflies, 1-deep rolled prefetch, K/q from [bh][t][D] (contiguous
// 192B-per-lane K reads). No atomics: partials to unique slots.
// ---------------------------------------------------------------------------
__global__ __launch_bounds__(256) void attn_kernel(
    const bf16* __restrict__ qg, const bf16* __restrict__ kg,
    const float* __restrict__ vwg, const float* __restrict__ biasg,
    const float* __restrict__ dpg, float* __restrict__ part)
{
  __shared__ __align__(16) float ql[64 * 26];
  int blk = blockIdx.x;             // 0..4095
  int b = blk & 31;                 // same-b -> same XCD (blk%8 == b%8)
  int u = blk >> 5;
  int h = u & 31;
  int st = (u >> 5) * 64;           // s-tile: 0,64,128,192
  int bh = b * H_ + h;
  int tid = threadIdx.x, wave = tid >> 6, lane = tid & 63;
  int t0 = lane * 4;

  // ---- K rows t0..t0+3 -> f32x2 regs (12 x 16B contiguous per lane) ----
  f32x2 kr[4][12];
  {
    const short8* kp = reinterpret_cast<const short8*>(
        kg + ((size_t)bh * S_ + t0) * D_);   // 4 rows x 24 bf16 = 12 short8
    #pragma unroll
    for (int v = 0; v < 12; v++) {
      short8 kk = kp[v];
      int row = v / 3, seg = v % 3;
      #pragma unroll
      for (int p2 = 0; p2 < 4; p2++) {
        union { short u; bf16 bb; } a, c;
        a.u = kk[2 * p2]; c.u = kk[2 * p2 + 1];
        f32x2 t2; t2.x = (float)a.bb; t2.y = (float)c.bb;
        kr[row][seg * 4 + p2] = t2;
      }
    }
  }
  // ---- vw for this lane's 4 t's, 3 dims ----
  float vwr[3][4];
  #pragma unroll
  for (int x = 0; x < 3; x++) {
    float4 v4 = *reinterpret_cast<const float4*>(
        vwg + (((size_t)x * B_ + b) * H_ + h) * S_ + t0);
    vwr[x][0] = v4.x; vwr[x][1] = v4.y; vwr[x][2] = v4.z; vwr[x][3] = v4.w;
  }
  // ---- stage q tile (64 rows x 24) as f32 in LDS ----
  {
    int r = tid >> 2, c0 = (tid & 3) * 6;
    const bf16* qrow = qg + ((size_t)bh * S_ + st + r) * D_ + c0;
    #pragma unroll
    for (int i = 0; i < 6; i++) ql[r * 26 + c0 + i] = (float)qrow[i];
  }
  __syncthreads();

  const float* biasbh = biasg + (size_t)bh * S_ * S_;
  const float* dpb    = dpg + (size_t)b * S_ * S_ * 3;

  // 1-deep prefetch (iteration 0, row = wave)
  float4 nb, nd0, nd1, nd2;
  {
    int s0 = st + wave;
    nb = *reinterpret_cast<const float4*>(biasbh + (size_t)s0 * S_ + t0);
    const float* dpr = dpb + (size_t)s0 * S_ * 3 + (size_t)t0 * 3;
    nd0 = *reinterpret_cast<const float4*>(dpr);
    nd1 = *reinterpret_cast<const float4*>(dpr + 4);
    nd2 = *reinterpret_cast<const float4*>(dpr + 8);
  }

  for (int si = 0; si < 16; si++) {
    float4 bias4 = nb, e0 = nd0, e1 = nd1, e2 = nd2;
    // issue next row's loads before compute
    int nsi = (si + 1 < 16) ? si + 1 : 0;    // last iter: dummy (L2-hot)
    int ns = st + nsi * 4 + wave;
    nb = *reinterpret_cast<const float4*>(biasbh + (size_t)ns * S_ + t0);
    const float* dpn = dpb + (size_t)ns * S_ * 3 + (size_t)t0 * 3;
    nd0 = *reinterpret_cast<const float4*>(dpn);
    nd1 = *reinterpret_cast<const float4*>(dpn + 4);
    nd2 = *reinterpret_cast<const float4*>(dpn + 8);

    int sr = si * 4 + wave;                  // row within tile
    int s  = st + sr;

    // scores for this lane's 4 t's (q broadcast from LDS, K in regs)
    f32x2 sc2[4];
    #pragma unroll
    for (int j = 0; j < 4; j++) { sc2[j].x = 0.f; sc2[j].y = 0.f; }
    #pragma unroll
    for (int i = 0; i < 12; i++) {
      f32x2 qd = *reinterpret_cast<const f32x2*>(&ql[sr * 26 + 2 * i]);
      #pragma unroll
      for (int j = 0; j < 4; j++) sc2[j] += qd * kr[j][i];
    }
    // constant shift -4 == exact softmax (scores O(10), fp32 range safe)
    float p[4];
    p[0] = __expf(sc2[0].x + sc2[0].y + bias4.x - 4.0f);
    p[1] = __expf(sc2[1].x + sc2[1].y + bias4.y - 4.0f);
    p[2] = __expf(sc2[2].x + sc2[2].y + bias4.z - 4.0f);
    p[3] = __expf(sc2[3].x + sc2[3].y + bias4.w - 4.0f);
    float l = (p[0] + p[1]) + (p[2] + p[3]);

    // dp unpack (t-major xyz) from the 3 float4s
    float dx[4] = {e0.x, e0.w, e1.z, e2.y};
    float dy[4] = {e0.y, e1.x, e1.w, e2.z};
    float dz[4] = {e0.z, e1.y, e2.x, e2.w};

    float ax = 0.f, ay = 0.f, az = 0.f;
    #pragma unroll
    for (int j = 0; j < 4; j++) {
      ax = fmaf(p[j] * dx[j], vwr[0][j], ax);
      ay = fmaf(p[j] * dy[j], vwr[1][j], ay);
      az = fmaf(p[j] * dz[j], vwr[2][j], az);
    }
    // 4 parallel butterflies
    #pragma unroll
    for (int o = 32; o; o >>= 1) {
      ax += __shfl_xor(ax, o);
      ay += __shfl_xor(ay, o);
      az += __shfl_xor(az, o);
      l  += __shfl_xor(l, o);
    }
    if (lane == 0) {
      float inv = 1.0f / l;
      float* op = part + ((size_t)bh * S_ + s) * 3;
      op[0] = ax * inv; op[1] = ay * inv; op[2] = az * inv;
    }
  }
}

// ---------------------------------------------------------------------------
// Sum partials over h: out[b][s][x] = sum_h part[(b*H+h)][s][x].
// Every d_out element written exactly once (tripwire-safe, no atomics).
// ---------------------------------------------------------------------------
__global__ __launch_bounds__(256) void reduce_h(
    const float* __restrict__ part, float* __restrict__ out)
{
  int k = blockIdx.x * 256 + threadIdx.x;   // 0 .. B_*S_*3-1 (grid exact)
  int b = k / (S_ * 3);
  int r = k - b * (S_ * 3);                 // s*3 + x
  const float* p = part + (size_t)b * H_ * S_ * 3 + r;
  float acc = 0.f;
  #pragma unroll
  for (int h = 0; h < H_; h++) acc += p[(size_t)h * S_ * 3];
  out[k] = acc;
}

// ---------------------------------------------------------------------------
extern "C" void kernel_launch(void* const* d_in, const int* in_sizes, int n_in,
                              void* d_out, int out_size, void* d_ws, size_t ws_size,
                              hipStream_t stream)
{
  const float* feats     = (const float*)d_in[0];
  const float* attn_bias = (const float*)d_in[1];
  const float* delta_pos = (const float*)d_in[2];
  const float* Wq        = (const float*)d_in[3];
  const float* bq        = (const float*)d_in[4];
  const float* Wk        = (const float*)d_in[5];
  const float* bk        = (const float*)d_in[6];
  const float* Wv        = (const float*)d_in[7];
  const float* bv        = (const float*)d_in[8];
  const float* Wfx       = (const float*)d_in[9];
  const float* Wfy       = (const float*)d_in[10];
  const float* Wfz       = (const float*)d_in[11];

  char* ws = (char*)d_ws;
  size_t off = 0;
  auto alloc = [&](size_t bytes) -> void* {
    void* p = ws + off;
    off = (off + bytes + 255) & ~(size_t)255;
    return p;
  };
  bf16*  ws_fb   = (bf16*) alloc((size_t)B_ * S_ * E_ * 2);        // feats bf16
  bf16*  ws_q    = (bf16*) alloc((size_t)B_ * H_ * S_ * D_ * 2);   // [bh][s][D]
  bf16*  ws_k    = (bf16*) alloc((size_t)B_ * H_ * S_ * D_ * 2);   // [bh][t][D]
  float* ws_vw   = (float*)alloc((size_t)3 * B_ * H_ * S_ * 4);
  bf16*  ws_Wt   = (bf16*) alloc((size_t)NTOT * E_ * 2);
  float* ws_bias = (float*)alloc((size_t)NTOT * 4);
  float* ws_part = (float*)alloc((size_t)B_ * H_ * S_ * 3 * 4);    // h-partials

  prep_fused<<<CAST_BLKS + QK_BLKS + VW_BLKS, 256, 0, stream>>>(
      feats, ws_fb, Wq, Wk, Wv, bq, bk, bv, Wfx, Wfy, Wfz, ws_Wt, ws_bias);

  gemm_qkv<<<dim3(NTOT / 128, B_ * S_ / 128), 256, 0, stream>>>(
      ws_fb, ws_Wt, ws_bias, ws_q, ws_k, ws_vw);

  attn_kernel<<<B_ * H_ * 4, 256, 0, stream>>>(ws_q, ws_k, ws_vw, attn_bias,
                                               delta_pos, ws_part);

  reduce_h<<<(B_ * S_ * 3) / 256, 256, 0, stream>>>(ws_part, (float*)d_out);
}

// Round 12
// 531.333 us; speedup vs baseline: 1.0379x; 1.0149x over previous
//
#include <hip/hip_runtime.h>
#include <hip/hip_bf16.h>

#define B_ 32
#define S_ 256
#define E_ 768
#define H_ 32
#define D_ 24
#define NTOT 1664   // 768 (q) + 768 (k) + 96 (vw) + 32 pad

typedef __hip_bfloat16 bf16;
typedef __attribute__((ext_vector_type(8))) short short8;
typedef __attribute__((ext_vector_type(4))) float floatx4;
typedef __attribute__((ext_vector_type(2))) float f32x2;

// global_load_lds width=16: wave-uniform LDS base + lane*16B linear dest.
#define GLOAD_LDS16(g, l)                                          \
  __builtin_amdgcn_global_load_lds(                                \
      (const __attribute__((address_space(1))) void*)(g),          \
      (__attribute__((address_space(3))) void*)(l), 16, 0, 0)

// grid partition of the fused prep kernel
#define CAST_BLKS 6144   // B*S*E/4/256
#define QK_BLKS   288    // 24 x 12 tiles of 64x64
#define VW_BLKS   391    // (128*E + NTOT + 255)/256

// ---------------------------------------------------------------------------
// prep_fused: cast + weight transpose + vw/bias in one dispatch (verbatim
// sections, grid-partitioned).
// ---------------------------------------------------------------------------
__global__ __launch_bounds__(256) void prep_fused(
    const float* __restrict__ feats, bf16* __restrict__ fb,
    const float* __restrict__ Wq, const float* __restrict__ Wk,
    const float* __restrict__ Wv,
    const float* __restrict__ bq, const float* __restrict__ bk,
    const float* __restrict__ bv,
    const float* __restrict__ Wfx, const float* __restrict__ Wfy,
    const float* __restrict__ Wfz,
    bf16* __restrict__ Wt, float* __restrict__ biasf)
{
  __shared__ float tile[64][65];
  const float qscale = 0.20412414523193154f;  // 24^-0.5
  int bid = blockIdx.x;

  if (bid < CAST_BLKS) {
    // ---- cast_feats ----
    int i = bid * 256 + threadIdx.x;
    float4 v = reinterpret_cast<const float4*>(feats)[i];
    union { ushort4 u; bf16 b[4]; } pk;
    pk.b[0] = (bf16)v.x; pk.b[1] = (bf16)v.y;
    pk.b[2] = (bf16)v.z; pk.b[3] = (bf16)v.w;
    reinterpret_cast<ushort4*>(fb)[i] = pk.u;
    return;
  }
  if (bid < CAST_BLKS + QK_BLKS) {
    // ---- prep_qk (64x64 transpose tile) ----
    int id = bid - CAST_BLKS;
    int n0 = (id % 24) * 64;                  // 0..1535
    int k0 = (id / 24) * 64;                  // 0..767
    int j = threadIdx.x & 63, i4 = threadIdx.x >> 6;
    bool isq = (n0 < 768);                    // uniform per block
    const float* W = isq ? Wq : Wk;
    int nc = isq ? n0 : n0 - 768;
    float sc = isq ? qscale : 1.0f;
    #pragma unroll
    for (int r = 0; r < 16; r++) {
      int i = r * 4 + i4;
      tile[i][j] = W[(size_t)(k0 + i) * E_ + nc + j] * sc;
    }
    __syncthreads();
    #pragma unroll
    for (int r = 0; r < 16; r++) {
      int jj = r * 4 + i4;
      Wt[(size_t)(n0 + jj) * E_ + k0 + j] = (bf16)tile[j][jj];
    }
    return;
  }
  // ---- prep_vw_bias ----
  int gid = (bid - CAST_BLKS - QK_BLKS) * 256 + threadIdx.x;
  if (gid < 128 * E_) {
    int n = 1536 + gid / E_, k = gid % E_;
    float val = 0.f;
    if (n < 1632) {
      int nn = n - 1536, x = nn >> 5, h = nn & 31;
      const float* Wf = (x == 0) ? Wfx : (x == 1 ? Wfy : Wfz);
      #pragma unroll
      for (int c = 0; c < D_; c++)
        val += Wv[(size_t)k * E_ + h * D_ + c] * Wf[h * D_ + c];
    }
    Wt[(size_t)n * E_ + k] = (bf16)val;
  } else {
    int n = gid - 128 * E_;
    if (n < NTOT) {
      float val;
      if (n < 768) {
        val = bq[n] * qscale;
      } else if (n < 1536) {
        val = bk[n - 768];
      } else if (n < 1632) {
        int nn = n - 1536, x = nn >> 5, h = nn & 31;
        const float* Wf = (x == 0) ? Wfx : (x == 1 ? Wfy : Wfz);
        float s = 0.f;
        #pragma unroll
        for (int c = 0; c < D_; c++)
          s += bv[h * D_ + c] * Wf[h * D_ + c];
        val = s;
      } else {
        val = 0.f;
      }
      biasf[n] = val;
    }
  }
}

// ---------------------------------------------------------------------------
// gemm_qkv v11: BK 32->64 — the kernel is BARRIER-DRAIN-bound (24 full
// vmcnt(0)+barrier drains for K=768), so halve the drain count: 12 iters of
// {8x global_load_lds16, barrier, 32 MFMA}. LDS 32KB ([128][64] x2, linear
// rows for DMA). 8-chunk XOR involution (extends v9's verified 4-chunk):
// source chunk (l&7)^((l>>3)&7) [row&7 call-invariant: calls step 32 rows],
// fragment reads chunk (quad+kk*4)^(row&7) -> 16-way bank conflict becomes
// 2-way (free). Epilogue [bh][t][D] unchanged.
// ---------------------------------------------------------------------------
__global__ __launch_bounds__(256) void gemm_qkv(
    const bf16* __restrict__ A, const bf16* __restrict__ Wt,
    const float* __restrict__ biasf,
    bf16* __restrict__ qout, bf16* __restrict__ kout,
    float* __restrict__ vwout)
{
  __shared__ __align__(16) short As[128 * 64];
  __shared__ __align__(16) short Bs[128 * 64];
  int tid = threadIdx.x;
  int m0 = blockIdx.y * 128, n0 = blockIdx.x * 128;
  int wave = tid >> 6, lane = tid & 63;
  int wm = (wave >> 1) * 64, wn = (wave & 1) * 64;
  int fr = lane & 15, quad = lane >> 4;

  // staging: call j covers rows j*32 + (tid>>3), col chunk (tid&7) of 8.
  // row&7 == (tid>>3)&7 for every call (j*32 ≡ 0 mod 8) -> source XOR
  // chunk is call-invariant. Dest is LINEAR: base + lane*16B.
  int srow = tid >> 3;                            // 0..31
  int schunk = (tid & 7) ^ (srow & 7);            // XOR-swizzled source chunk
  const bf16* Asrc = A + (size_t)(m0 + srow) * E_ + schunk * 8;
  const bf16* Bsrc = Wt + (size_t)(n0 + srow) * E_ + schunk * 8;
  short* AsW = As + wave * 512;                   // (wave*8 rows)*64
  short* BsW = Bs + wave * 512;

  floatx4 acc[4][4];
  const floatx4 zero = {0.f, 0.f, 0.f, 0.f};
  #pragma unroll
  for (int i = 0; i < 4; i++)
    #pragma unroll
    for (int j = 0; j < 4; j++) acc[i][j] = zero;

  // fragment read offsets (shorts): row r, K-chunk c -> r*64 + (c^(r&7))*8
  int ra[4][2], rb[4][2];
  #pragma unroll
  for (int t = 0; t < 4; t++) {
    int rowa = wm + t * 16 + fr;
    int rowb = wn + t * 16 + fr;
    #pragma unroll
    for (int kk = 0; kk < 2; kk++) {
      ra[t][kk] = rowa * 64 + (((quad + kk * 4) ^ (rowa & 7)) * 8);
      rb[t][kk] = rowb * 64 + (((quad + kk * 4) ^ (rowb & 7)) * 8);
    }
  }

  for (int k0 = 0; k0 < E_; k0 += 64) {
    if (k0) __syncthreads();        // previous iter's frag reads complete
    #pragma unroll
    for (int j = 0; j < 4; j++) {
      GLOAD_LDS16(Asrc + (size_t)(j * 32) * E_ + k0, AsW + j * 2048);
      GLOAD_LDS16(Bsrc + (size_t)(j * 32) * E_ + k0, BsW + j * 2048);
    }
    __syncthreads();                // vmcnt(0) drained before barrier
    #pragma unroll
    for (int kk = 0; kk < 2; kk++) {
      short8 af[4], bfr[4];
      #pragma unroll
      for (int t = 0; t < 4; t++)
        af[t] = *reinterpret_cast<const short8*>(&As[ra[t][kk]]);
      #pragma unroll
      for (int t = 0; t < 4; t++)
        bfr[t] = *reinterpret_cast<const short8*>(&Bs[rb[t][kk]]);
      #pragma unroll
      for (int ti = 0; ti < 4; ti++)
        #pragma unroll
        for (int tj = 0; tj < 4; tj++)
          acc[ti][tj] = __builtin_amdgcn_mfma_f32_16x16x32_bf16(
              af[ti], bfr[tj], acc[ti][tj], 0, 0, 0);
    }
  }

  // epilogue: C/D layout col = lane&15, row = quad*4 + r; [bh][t][D] writes
  #pragma unroll
  for (int ti = 0; ti < 4; ti++) {
    #pragma unroll
    for (int tj = 0; tj < 4; tj++) {
      int n = n0 + wn + tj * 16 + fr;
      float bias = biasf[n];
      #pragma unroll
      for (int r = 0; r < 4; r++) {
        int m = m0 + wm + ti * 16 + quad * 4 + r;
        int b = m >> 8, s = m & 255;
        float val = acc[ti][tj][r] + bias;
        if (n < 768) {
          int h = n / 24, d = n - h * 24;
          qout[(((size_t)b * H_ + h) * S_ + s) * D_ + d] = (bf16)val;
        } else if (n < 1536) {
          int n2 = n - 768;
          int h = n2 / 24, d = n2 - h * 24;
          kout[(((size_t)b * H_ + h) * S_ + s) * D_ + d] = (bf16)val;
        } else if (n < 1632) {
          int nn = n - 1536, x = nn >> 5, hh = nn & 31;
          vwout[(((size_t)x * B_ + b) * H_ + hh) * S_ + s] = val;
        }
      }
    }
  }
}

// ---------------------------------------------------------------------------
// Attention (unchanged, measured 172us): wave-owns-s, lanes-own-t, coalesced
// bias/dp streams, shifted softmax (exact), 4 parallel butterflies, 1-deep
// rolled prefetch, K/q from [bh][t][D]. Partials to unique slots (no atomics).
// ---------------------------------------------------------------------------
__global__ __launch_bounds__(256) void attn_kernel(
    const bf16* __restrict__ qg, const bf16* __restrict__ kg,
    const float* __restrict__ vwg, const float* __restrict__ biasg,
    const float* __restrict__ dpg, float* __restrict__ part)
{
  __shared__ __align__(16) float ql[64 * 26];
  int blk = blockIdx.x;             // 0..4095
  int b = blk & 31;                 // same-b -> same XCD (blk%8 == b%8)
  int u = blk >> 5;
  int h = u & 31;
  int st = (u >> 5) * 64;           // s-tile: 0,64,128,192
  int bh = b * H_ + h;
  int tid = threadIdx.x, wave = tid >> 6, lane = tid & 63;
  int t0 = lane * 4;

  // ---- K rows t0..t0+3 -> f32x2 regs (12 x 16B contiguous per lane) ----
  f32x2 kr[4][12];
  {
    const short8* kp = reinterpret_cast<const short8*>(
        kg + ((size_t)bh * S_ + t0) * D_);   // 4 rows x 24 bf16 = 12 short8
    #pragma unroll
    for (int v = 0; v < 12; v++) {
      short8 kk = kp[v];
      int row = v / 3, seg = v % 3;
      #pragma unroll
      for (int p2 = 0; p2 < 4; p2++) {
        union { short u; bf16 bb; } a, c;
        a.u = kk[2 * p2]; c.u = kk[2 * p2 + 1];
        f32x2 t2; t2.x = (float)a.bb; t2.y = (float)c.bb;
        kr[row][seg * 4 + p2] = t2;
      }
    }
  }
  // ---- vw for this lane's 4 t's, 3 dims ----
  float vwr[3][4];
  #pragma unroll
  for (int x = 0; x < 3; x++) {
    float4 v4 = *reinterpret_cast<const float4*>(
        vwg + (((size_t)x * B_ + b) * H_ + h) * S_ + t0);
    vwr[x][0] = v4.x; vwr[x][1] = v4.y; vwr[x][2] = v4.z; vwr[x][3] = v4.w;
  }
  // ---- stage q tile (64 rows x 24) as f32 in LDS ----
  {
    int r = tid >> 2, c0 = (tid & 3) * 6;
    const bf16* qrow = qg + ((size_t)bh * S_ + st + r) * D_ + c0;
    #pragma unroll
    for (int i = 0; i < 6; i++) ql[r * 26 + c0 + i] = (float)qrow[i];
  }
  __syncthreads();

  const float* biasbh = biasg + (size_t)bh * S_ * S_;
  const float* dpb    = dpg + (size_t)b * S_ * S_ * 3;

  // 1-deep prefetch (iteration 0, row = wave)
  float4 nb, nd0, nd1, nd2;
  {
    int s0 = st + wave;
    nb = *reinterpret_cast<const float4*>(biasbh + (size_t)s0 * S_ + t0);
    const float* dpr = dpb + (size_t)s0 * S_ * 3 + (size_t)t0 * 3;
    nd0 = *reinterpret_cast<const float4*>(dpr);
    nd1 = *reinterpret_cast<const float4*>(dpr + 4);
    nd2 = *reinterpret_cast<const float4*>(dpr + 8);
  }

  for (int si = 0; si < 16; si++) {
    float4 bias4 = nb, e0 = nd0, e1 = nd1, e2 = nd2;
    // issue next row's loads before compute
    int nsi = (si + 1 < 16) ? si + 1 : 0;    // last iter: dummy (L2-hot)
    int ns = st + nsi * 4 + wave;
    nb = *reinterpret_cast<const float4*>(biasbh + (size_t)ns * S_ + t0);
    const float* dpn = dpb + (size_t)ns * S_ * 3 + (size_t)t0 * 3;
    nd0 = *reinterpret_cast<const float4*>(dpn);
    nd1 = *reinterpret_cast<const float4*>(dpn + 4);
    nd2 = *reinterpret_cast<const float4*>(dpn + 8);

    int sr = si * 4 + wave;                  // row within tile
    int s  = st + sr;

    // scores for this lane's 4 t's (q broadcast from LDS, K in regs)
    f32x2 sc2[4];
    #pragma unroll
    for (int j = 0; j < 4; j++) { sc2[j].x = 0.f; sc2[j].y = 0.f; }
    #pragma unroll
    for (int i = 0; i < 12; i++) {
      f32x2 qd = *reinterpret_cast<const f32x2*>(&ql[sr * 26 + 2 * i]);
      #pragma unroll
      for (int j = 0; j < 4; j++) sc2[j] += qd * kr[j][i];
    }
    // constant shift -4 == exact softmax (scores O(10), fp32 range safe)
    float p[4];
    p[0] = __expf(sc2[0].x + sc2[0].y + bias4.x - 4.0f);
    p[1] = __expf(sc2[1].x + sc2[1].y + bias4.y - 4.0f);
    p[2] = __expf(sc2[2].x + sc2[2].y + bias4.z - 4.0f);
    p[3] = __expf(sc2[3].x + sc2[3].y + bias4.w - 4.0f);
    float l = (p[0] + p[1]) + (p[2] + p[3]);

    // dp unpack (t-major xyz) from the 3 float4s
    float dx[4] = {e0.x, e0.w, e1.z, e2.y};
    float dy[4] = {e0.y, e1.x, e1.w, e2.z};
    float dz[4] = {e0.z, e1.y, e2.x, e2.w};

    float ax = 0.f, ay = 0.f, az = 0.f;
    #pragma unroll
    for (int j = 0; j < 4; j++) {
      ax = fmaf(p[j] * dx[j], vwr[0][j], ax);
      ay = fmaf(p[j] * dy[j], vwr[1][j], ay);
      az = fmaf(p[j] * dz[j], vwr[2][j], az);
    }
    // 4 parallel butterflies
    #pragma unroll
    for (int o = 32; o; o >>= 1) {
      ax += __shfl_xor(ax, o);
      ay += __shfl_xor(ay, o);
      az += __shfl_xor(az, o);
      l  += __shfl_xor(l, o);
    }
    if (lane == 0) {
      float inv = 1.0f / l;
      float* op = part + ((size_t)bh * S_ + s) * 3;
      op[0] = ax * inv; op[1] = ay * inv; op[2] = az * inv;
    }
  }
}

// ---------------------------------------------------------------------------
// Sum partials over h: out[b][s][x] = sum_h part[(b*H+h)][s][x].
// Every d_out element written exactly once (tripwire-safe, no atomics).
// ---------------------------------------------------------------------------
__global__ __launch_bounds__(256) void reduce_h(
    const float* __restrict__ part, float* __restrict__ out)
{
  int k = blockIdx.x * 256 + threadIdx.x;   // 0 .. B_*S_*3-1 (grid exact)
  int b = k / (S_ * 3);
  int r = k - b * (S_ * 3);                 // s*3 + x
  const float* p = part + (size_t)b * H_ * S_ * 3 + r;
  float acc = 0.f;
  #pragma unroll
  for (int h = 0; h < H_; h++) acc += p[(size_t)h * S_ * 3];
  out[k] = acc;
}

// ---------------------------------------------------------------------------
extern "C" void kernel_launch(void* const* d_in, const int* in_sizes, int n_in,
                              void* d_out, int out_size, void* d_ws, size_t ws_size,
                              hipStream_t stream)
{
  const float* feats     = (const float*)d_in[0];
  const float* attn_bias = (const float*)d_in[1];
  const float* delta_pos = (const float*)d_in[2];
  const float* Wq        = (const float*)d_in[3];
  const float* bq        = (const float*)d_in[4];
  const float* Wk        = (const float*)d_in[5];
  const float* bk        = (const float*)d_in[6];
  const float* Wv        = (const float*)d_in[7];
  const float* bv        = (const float*)d_in[8];
  const float* Wfx       = (const float*)d_in[9];
  const float* Wfy       = (const float*)d_in[10];
  const float* Wfz       = (const float*)d_in[11];

  char* ws = (char*)d_ws;
  size_t off = 0;
  auto alloc = [&](size_t bytes) -> void* {
    void* p = ws + off;
    off = (off + bytes + 255) & ~(size_t)255;
    return p;
  };
  bf16*  ws_fb   = (bf16*) alloc((size_t)B_ * S_ * E_ * 2);        // feats bf16
  bf16*  ws_q    = (bf16*) alloc((size_t)B_ * H_ * S_ * D_ * 2);   // [bh][s][D]
  bf16*  ws_k    = (bf16*) alloc((size_t)B_ * H_ * S_ * D_ * 2);   // [bh][t][D]
  float* ws_vw   = (float*)alloc((size_t)3 * B_ * H_ * S_ * 4);
  bf16*  ws_Wt   = (bf16*) alloc((size_t)NTOT * E_ * 2);
  float* ws_bias = (float*)alloc((size_t)NTOT * 4);
  float* ws_part = (float*)alloc((size_t)B_ * H_ * S_ * 3 * 4);    // h-partials

  prep_fused<<<CAST_BLKS + QK_BLKS + VW_BLKS, 256, 0, stream>>>(
      feats, ws_fb, Wq, Wk, Wv, bq, bk, bv, Wfx, Wfy, Wfz, ws_Wt, ws_bias);

  gemm_qkv<<<dim3(NTOT / 128, B_ * S_ / 128), 256, 0, stream>>>(
      ws_fb, ws_Wt, ws_bias, ws_q, ws_k, ws_vw);

  attn_kernel<<<B_ * H_ * 4, 256, 0, stream>>>(ws_q, ws_k, ws_vw, attn_bias,
                                               delta_pos, ws_part);

  reduce_h<<<(B_ * S_ * 3) / 256, 256, 0, stream>>>(ws_part, (float*)d_out);
}